// Round 11
// baseline (23.743 us; speedup 1.0000x reference)
//
#include <hip/hip_runtime.h>

// SigNet forward, closed-form (scan-free) depth-3 signature + Linear.
// B=256, L=256, CIN=8, C=9, SIG_CH=819, OUT=128.
//
// s1[i]       = x_L[i]
// s2[i][j]    = sum_l w_l[i] * d_l[j]                   w = X - 0.5*D
// s3[i][j][k] = s2[i][j]*x_L[k]
//             + sum_l ( z_l[i]*d_l[j]*d_l[k] - w_l[i]*d_l[j]*X_l[k] )
//   with z = 0.5*X - D/3       (X = absolute path value at segment end)
//
// 576 threads = 9 waves; wave w owns channel i=w; lane owns float4-l-col.
// All LDS reads are distributed (1KB/instr, ~47 reads/wave total); the
// sum over l is a 6-step DPP v_add_f32 tree (pure VALU, result lane 63).
// kt-passes of 3 k's keep live regs ~90 (no spill even at a ~102 cap).

#define ROWF   260                 // table row stride in floats
#define DMPF   (2 * 9 * ROWF)      // dump base = 4680 floats
#define U1SZ   (DMPF + 9 * 108)    // + 9 i * (3 passes * 36) = 5652 floats

__device__ __forceinline__ float wave_sum64(float x) {
    // canonical gfx9 full-wave f32 sum via DPP; total lands in lane 63.
    // update_dpp(old=0,...): lanes with no valid source contribute 0.
#define DPPADD(CTRL) { \
    int r_ = __builtin_amdgcn_update_dpp(0, __float_as_int(x), CTRL, 0xF, 0xF, false); \
    x += __int_as_float(r_); }
    DPPADD(0x111)   // row_shr:1
    DPPADD(0x112)   // row_shr:2
    DPPADD(0x114)   // row_shr:4
    DPPADD(0x118)   // row_shr:8  -> lane15 of each row = row sum
    DPPADD(0x142)   // row_bcast:15 -> lane31 = rows0+1, lane63 = rows2+3
    DPPADD(0x143)   // row_bcast:31 -> lane63 = full sum
#undef DPPADD
    return x;
}

__global__ __launch_bounds__(576) void signet_fwd(
    const float* __restrict__ inp,   // [256, 256, 8]
    const float* __restrict__ Wg,    // [819, 128]
    const float* __restrict__ bias,  // [128]
    float* __restrict__ out)         // [256, 128]
{
    __shared__ float sig[820];
    __shared__ __align__(16) float u[U1SZ];

    float* Xt = u;                 // [9][260] (dead after main loop)
    float* Dt = u + 9 * ROWF;      // [9][260]

    const int tid  = threadIdx.x;
    const int b    = blockIdx.x;
    const int lane = tid & 63;
    const int wid  = tid >> 6;     // 0..8 = channel i

    // ---- prep: tables (column t = segment t+1, basepoint 0) + s1 = x_L ----
    if (tid < 512) {
        const int t = tid & 255;
        const float* rc = inp + (size_t)b * 2048 + (size_t)t * 8;
        if (tid < 256) {
            float4 c0 = *(const float4*)rc;
            float4 p0 = make_float4(0.f, 0.f, 0.f, 0.f);
            float  tp = 0.f;
            if (t > 0) { p0 = *(const float4*)(rc - 8); tp = (float)(t - 1) * (1.0f / 255.0f); }
            float cur[5] = { (float)t * (1.0f / 255.0f), c0.x, c0.y, c0.z, c0.w };
            float prv[5] = { tp, p0.x, p0.y, p0.z, p0.w };
            #pragma unroll
            for (int c = 0; c < 5; ++c) {
                Xt[c * ROWF + t] = cur[c];
                Dt[c * ROWF + t] = cur[c] - prv[c];
            }
        } else {
            float4 c1 = *(const float4*)(rc + 4);
            float4 p1 = make_float4(0.f, 0.f, 0.f, 0.f);
            if (t > 0) p1 = *(const float4*)(rc - 4);
            float cur[4] = { c1.x, c1.y, c1.z, c1.w };
            float prv[4] = { p1.x, p1.y, p1.z, p1.w };
            #pragma unroll
            for (int c = 0; c < 4; ++c) {
                Xt[(5 + c) * ROWF + t] = cur[c];
                Dt[(5 + c) * ROWF + t] = cur[c] - prv[c];
            }
        }
    }
    if (tid < 9) {
        sig[tid] = (tid == 0) ? 1.0f
                              : inp[(size_t)b * 2048 + 255 * 8 + (tid - 1)];
    }
    __syncthreads();

    // ---- main: wave = i, lane = float4-l-column; 3 kt-passes ----
    {
        const float4* X4 = (const float4*)u;          // [9][65]
        const float4* D4 = X4 + 9 * 65;
        const float4 Xi = X4[wid * 65 + lane];
        const float4 Di = D4[wid * 65 + lane];
        float4 w, z;
        w.x = fmaf(-0.5f, Di.x, Xi.x);
        w.y = fmaf(-0.5f, Di.y, Xi.y);
        w.z = fmaf(-0.5f, Di.z, Xi.z);
        w.w = fmaf(-0.5f, Di.w, Xi.w);
        z.x = fmaf(-(1.0f / 3.0f), Di.x, 0.5f * Xi.x);
        z.y = fmaf(-(1.0f / 3.0f), Di.y, 0.5f * Xi.y);
        z.z = fmaf(-(1.0f / 3.0f), Di.z, 0.5f * Xi.z);
        z.w = fmaf(-(1.0f / 3.0f), Di.w, 0.5f * Xi.w);

        float* dmp = u + DMPF + wid * 108;

        #pragma unroll
        for (int kt = 0; kt < 3; ++kt) {
            const float4 Xk0 = X4[(3 * kt + 0) * 65 + lane];
            const float4 Xk1 = X4[(3 * kt + 1) * 65 + lane];
            const float4 Xk2 = X4[(3 * kt + 2) * 65 + lane];
            const float4 Dk0 = D4[(3 * kt + 0) * 65 + lane];
            const float4 Dk1 = D4[(3 * kt + 1) * 65 + lane];
            const float4 Dk2 = D4[(3 * kt + 2) * 65 + lane];

            float a[9][3];
            float s2a[9];
            #pragma unroll
            for (int j = 0; j < 9; ++j) {
                const float4 Dj = D4[j * 65 + lane];
                float4 uu, vv;
                uu.x = w.x * Dj.x;  uu.y = w.y * Dj.y;
                uu.z = w.z * Dj.z;  uu.w = w.w * Dj.w;
                vv.x = z.x * Dj.x;  vv.y = z.y * Dj.y;
                vv.z = z.z * Dj.z;  vv.w = z.w * Dj.w;
                if (kt == 0) s2a[j] = (uu.x + uu.y) + (uu.z + uu.w);
                else         s2a[j] = 0.f;

                float t0 = fmaf(vv.x, Dk0.x, -uu.x * Xk0.x);
                t0 = fmaf(vv.y, Dk0.y, fmaf(-uu.y, Xk0.y, t0));
                t0 = fmaf(vv.z, Dk0.z, fmaf(-uu.z, Xk0.z, t0));
                t0 = fmaf(vv.w, Dk0.w, fmaf(-uu.w, Xk0.w, t0));
                a[j][0] = t0;

                float t1 = fmaf(vv.x, Dk1.x, -uu.x * Xk1.x);
                t1 = fmaf(vv.y, Dk1.y, fmaf(-uu.y, Xk1.y, t1));
                t1 = fmaf(vv.z, Dk1.z, fmaf(-uu.z, Xk1.z, t1));
                t1 = fmaf(vv.w, Dk1.w, fmaf(-uu.w, Xk1.w, t1));
                a[j][1] = t1;

                float t2 = fmaf(vv.x, Dk2.x, -uu.x * Xk2.x);
                t2 = fmaf(vv.y, Dk2.y, fmaf(-uu.y, Xk2.y, t2));
                t2 = fmaf(vv.z, Dk2.z, fmaf(-uu.z, Xk2.z, t2));
                t2 = fmaf(vv.w, Dk2.w, fmaf(-uu.w, Xk2.w, t2));
                a[j][2] = t2;
            }

            // cross-lane sum over l (DPP, result in lane 63)
            #pragma unroll
            for (int j = 0; j < 9; ++j) {
                a[j][0] = wave_sum64(a[j][0]);
                a[j][1] = wave_sum64(a[j][1]);
                a[j][2] = wave_sum64(a[j][2]);
                if (kt == 0) s2a[j] = wave_sum64(s2a[j]);
            }

            if (lane == 63) {
                float4* p = (float4*)(dmp + kt * 36);
                p[0] = make_float4(a[0][0], a[0][1], a[0][2], a[1][0]);
                p[1] = make_float4(a[1][1], a[1][2], a[2][0], a[2][1]);
                p[2] = make_float4(a[2][2], a[3][0], a[3][1], a[3][2]);
                p[3] = make_float4(a[4][0], a[4][1], a[4][2], a[5][0]);
                p[4] = make_float4(a[5][1], a[5][2], a[6][0], a[6][1]);
                p[5] = make_float4(a[6][2], a[7][0], a[7][1], a[7][2]);
                p[6] = make_float4(a[8][0], a[8][1], a[8][2],
                                   (kt == 0) ? s2a[0] : 0.f);
                if (kt == 0) {
                    p[7] = make_float4(s2a[1], s2a[2], s2a[3], s2a[4]);
                    p[8] = make_float4(s2a[5], s2a[6], s2a[7], s2a[8]);
                }
            }
        }
    }
    __syncthreads();

    // ---- combine: s2/s3 are already full sums; add cross-term ----
    for (int e = tid; e < 810; e += 576) {
        if (e < 729) {
            const int i3 = e / 81;
            const int r  = e - i3 * 81;
            const int j3 = r / 9;
            const int k3 = r - j3 * 9;
            const int kt = k3 / 3;
            const int km = k3 - kt * 3;
            const float v   = u[DMPF + i3 * 108 + kt * 36 + j3 * 3 + km];
            const float s2v = u[DMPF + i3 * 108 + 27 + j3];
            sig[90 + e] = fmaf(s2v, sig[k3], v);
        } else {
            const int q  = e - 729;
            const int i2 = q / 9;
            const int j2 = q - i2 * 9;
            sig[9 + q] = u[DMPF + i2 * 108 + 27 + j2];
        }
    }
    __syncthreads();

    // ---- linear: out[b][o] = bias[o] + sum_ch sig[ch]*Wg[ch][o] ----
    {
        const int oq = tid & 31;     // outputs 4*oq..4*oq+3
        const int sl = tid >> 5;     // channel slice 0..17
        float4 acc = make_float4(0.f, 0.f, 0.f, 0.f);
        const float4* Wq = (const float4*)Wg;
        for (int ch = sl; ch < 819; ch += 18) {
            const float s = sig[ch];
            const float4 wv = Wq[(size_t)ch * 32 + oq];
            acc.x = fmaf(s, wv.x, acc.x);
            acc.y = fmaf(s, wv.y, acc.y);
            acc.z = fmaf(s, wv.z, acc.z);
            acc.w = fmaf(s, wv.w, acc.w);
        }
        float4* pbuf = (float4*)u;               // aliases dead tables
        pbuf[sl * 32 + oq] = acc;
    }
    __syncthreads();
    if (tid < 32) {
        const float4* pbuf = (const float4*)u;
        float4 r = pbuf[tid];
        #pragma unroll
        for (int s = 1; s < 18; ++s) {
            const float4 p = pbuf[s * 32 + tid];
            r.x += p.x; r.y += p.y; r.z += p.z; r.w += p.w;
        }
        const float4 bv = ((const float4*)bias)[tid];
        r.x += bv.x; r.y += bv.y; r.z += bv.z; r.w += bv.w;
        ((float4*)(out + (size_t)b * 128))[tid] = r;
    }
}

extern "C" void kernel_launch(void* const* d_in, const int* in_sizes, int n_in,
                              void* d_out, int out_size, void* d_ws, size_t ws_size,
                              hipStream_t stream) {
    const float* inp  = (const float*)d_in[0];
    const float* Wp   = (const float*)d_in[1];
    const float* bias = (const float*)d_in[2];
    float* outp = (float*)d_out;
    (void)in_sizes; (void)n_in; (void)out_size; (void)d_ws; (void)ws_size;

    hipLaunchKernelGGL(signet_fwd, dim3(256), dim3(576), 0, stream,
                       inp, Wp, bias, outp);
}

// Round 12
// 18.057 us; speedup vs baseline: 1.3149x; 1.3149x over previous
//
#include <hip/hip_runtime.h>

// SigNet forward, closed-form (scan-free) depth-3 signature + Linear.
// B=256, L=256, CIN=8, C=9, SIG_CH=819, OUT=128.
//
// s1[i]       = x_L[i]
// s2[i][j]    = sum_l w_l[i] * d_l[j]                   w = X - 0.5*D
// s3[i][j][k] = s2[i][j]*x_L[k]
//             + sum_l ( z_l[i]*d_l[j]*d_l[k] - w_l[i]*d_l[j]*X_l[k] )
//   with z = 0.5*X - D/3       (X = absolute path value at segment end)
//
// Block = 704 threads (11 waves): 648 active (8 l-ranges x 81 (i,jt,kt)
// owners) = 92% lane utilization (R10 used 1024 -> 63%), and the 11-wave
// block raises the VGPR budget off the 64 cap (1024-thread artifact,
// R7-R9) so the 8 q-iterations can be pipelined. 12 accumulators/thread.

#define RANGES  8
#define TPR     81
#define NACT    (RANGES * TPR)        // 648
#define PSTR    13                    // dump stride (odd -> conflict-free)
#define U1SZ    (NACT * PSTR)         // 8424 floats; tables (4680) alias front
#define NSL     22                    // epilogue W-slices (704/32)

__global__ __launch_bounds__(704) void signet_fwd(
    const float* __restrict__ inp,   // [256, 256, 8]
    const float* __restrict__ Wg,    // [819, 128]
    const float* __restrict__ bias,  // [128]
    float* __restrict__ out)         // [256, 128]
{
    __shared__ float sig[820];
    __shared__ __align__(16) float u[U1SZ];

    float* Xt = u;                 // [9][260] floats (dead after main loop)
    float* Dt = u + 9 * 260;

    const int tid = threadIdx.x;
    const int b   = blockIdx.x;

    // ---- prep: tables (column t = segment t+1, basepoint 0) + s1 = x_L ----
    if (tid < 512) {
        const int t = tid & 255;
        const float* rc = inp + (size_t)b * 2048 + (size_t)t * 8;
        if (tid < 256) {
            float4 c0 = *(const float4*)rc;
            float4 p0 = make_float4(0.f, 0.f, 0.f, 0.f);
            float  tp = 0.f;
            if (t > 0) { p0 = *(const float4*)(rc - 8); tp = (float)(t - 1) * (1.0f / 255.0f); }
            float cur[5] = { (float)t * (1.0f / 255.0f), c0.x, c0.y, c0.z, c0.w };
            float prv[5] = { tp, p0.x, p0.y, p0.z, p0.w };
            #pragma unroll
            for (int c = 0; c < 5; ++c) {
                Xt[c * 260 + t] = cur[c];
                Dt[c * 260 + t] = cur[c] - prv[c];
            }
        } else {
            float4 c1 = *(const float4*)(rc + 4);
            float4 p1 = make_float4(0.f, 0.f, 0.f, 0.f);
            if (t > 0) p1 = *(const float4*)(rc - 4);
            float cur[4] = { c1.x, c1.y, c1.z, c1.w };
            float prv[4] = { p1.x, p1.y, p1.z, p1.w };
            #pragma unroll
            for (int c = 0; c < 4; ++c) {
                Xt[(5 + c) * 260 + t] = cur[c];
                Dt[(5 + c) * 260 + t] = cur[c] - prv[c];
            }
        }
    }
    if (tid < 9) {
        sig[tid] = (tid == 0) ? 1.0f
                              : inp[(size_t)b * 2048 + 255 * 8 + (tid - 1)];
    }
    __syncthreads();

    // ---- main: range rr = tid/81 handles float4 cols [rr*8, rr*8+8) ----
    const bool act = (tid < NACT);
    const int  rr  = tid / TPR;
    const int  lt  = tid - rr * TPR;     // 0..80
    const int  ii  = lt / 9;             // channel i
    const int  jk  = lt - ii * 9;
    const int  jt  = jk / 3;             // j-triple: j = 3*jt+jm
    const int  kt  = jk - jt * 3;        // k-triple: k = 3*kt+km

    float a[3][3];                       // [jm][km]
    float s2a[3];
    #pragma unroll
    for (int jm = 0; jm < 3; ++jm) {
        s2a[jm] = 0.f;
        a[jm][0] = 0.f; a[jm][1] = 0.f; a[jm][2] = 0.f;
    }

    if (act) {
        const float4* X4 = (const float4*)u;             // [9][65]
        const float4* D4 = (const float4*)u + 9 * 65;

        #pragma unroll
        for (int q = 0; q < 8; ++q) {
            const int idx = rr * 8 + q;
            const float4 Xi = X4[ii * 65 + idx];
            const float4 Di = D4[ii * 65 + idx];
            float4 w, z;
            w.x = fmaf(-0.5f, Di.x, Xi.x);
            w.y = fmaf(-0.5f, Di.y, Xi.y);
            w.z = fmaf(-0.5f, Di.z, Xi.z);
            w.w = fmaf(-0.5f, Di.w, Xi.w);
            z.x = fmaf(-(1.0f / 3.0f), Di.x, 0.5f * Xi.x);
            z.y = fmaf(-(1.0f / 3.0f), Di.y, 0.5f * Xi.y);
            z.z = fmaf(-(1.0f / 3.0f), Di.z, 0.5f * Xi.z);
            z.w = fmaf(-(1.0f / 3.0f), Di.w, 0.5f * Xi.w);

            float4 uu[3], vv[3];
            #pragma unroll
            for (int jm = 0; jm < 3; ++jm) {
                const float4 Dj = D4[(3 * jt + jm) * 65 + idx];
                uu[jm].x = w.x * Dj.x;  uu[jm].y = w.y * Dj.y;
                uu[jm].z = w.z * Dj.z;  uu[jm].w = w.w * Dj.w;
                vv[jm].x = z.x * Dj.x;  vv[jm].y = z.y * Dj.y;
                vv[jm].z = z.z * Dj.z;  vv[jm].w = z.w * Dj.w;
                s2a[jm] += (uu[jm].x + uu[jm].y) + (uu[jm].z + uu[jm].w);
            }
            #pragma unroll
            for (int km = 0; km < 3; ++km) {
                const float4 Xk = X4[(3 * kt + km) * 65 + idx];
                const float4 Dk = D4[(3 * kt + km) * 65 + idx];
                #pragma unroll
                for (int jm = 0; jm < 3; ++jm) {
                    a[jm][km] = fmaf(vv[jm].x, Dk.x, fmaf(-uu[jm].x, Xk.x, a[jm][km]));
                    a[jm][km] = fmaf(vv[jm].y, Dk.y, fmaf(-uu[jm].y, Xk.y, a[jm][km]));
                    a[jm][km] = fmaf(vv[jm].z, Dk.z, fmaf(-uu[jm].z, Xk.z, a[jm][km]));
                    a[jm][km] = fmaf(vv[jm].w, Dk.w, fmaf(-uu[jm].w, Xk.w, a[jm][km]));
                }
            }
        }
    }
    __syncthreads();   // last table read above; dump may now alias tables

    // ---- dump partials (12 floats/thread, stride 13) ----
    if (act) {
        float* pa = u + tid * PSTR;
        #pragma unroll
        for (int jm = 0; jm < 3; ++jm) {
            pa[jm * 3 + 0] = a[jm][0];
            pa[jm * 3 + 1] = a[jm][1];
            pa[jm * 3 + 2] = a[jm][2];
        }
        pa[9]  = s2a[0];
        pa[10] = s2a[1];
        pa[11] = s2a[2];
    }
    __syncthreads();

    // ---- combine s2 -> sig[9..89] ----
    if (tid < 81) {
        const int i2  = tid / 9;
        const int j2  = tid - i2 * 9;
        const int jt2 = j2 / 3;
        const int jm2 = j2 - jt2 * 3;
        const int base = (i2 * 9 + jt2 * 3) * PSTR + 9 + jm2;   // kt == 0 thread
        float s = 0.f;
        #pragma unroll
        for (int c = 0; c < RANGES; ++c) s += u[c * TPR * PSTR + base];
        sig[9 + tid] = s;
    }
    __syncthreads();

    // ---- combine s3 -> sig[90..818] ----
    for (int e = tid; e < 729; e += 704) {
        const int i3  = e / 81;
        const int rem = e - i3 * 81;
        const int j3  = rem / 9;
        const int k3  = rem - j3 * 9;
        const int jt3 = j3 / 3, jm3 = j3 - jt3 * 3;
        const int kt3 = k3 / 3, km3 = k3 - kt3 * 3;
        const int base = (i3 * 9 + jt3 * 3 + kt3) * PSTR + jm3 * 3 + km3;
        float s = 0.f;
        #pragma unroll
        for (int c = 0; c < RANGES; ++c) s += u[c * TPR * PSTR + base];
        s = fmaf(sig[9 + i3 * 9 + j3], sig[k3], s);
        sig[90 + e] = s;
    }
    __syncthreads();

    // ---- linear: out[b][o] = bias[o] + sum_ch sig[ch]*Wg[ch][o] ----
    {
        const int oq = tid & 31;     // outputs 4*oq..4*oq+3
        const int sl = tid >> 5;     // channel slice 0..21
        float4 acc = make_float4(0.f, 0.f, 0.f, 0.f);
        const float4* Wq = (const float4*)Wg;
        for (int ch = sl; ch < 819; ch += NSL) {
            const float s = sig[ch];
            const float4 wv = Wq[(size_t)ch * 32 + oq];
            acc.x = fmaf(s, wv.x, acc.x);
            acc.y = fmaf(s, wv.y, acc.y);
            acc.z = fmaf(s, wv.z, acc.z);
            acc.w = fmaf(s, wv.w, acc.w);
        }
        float4* pbuf = (float4*)u;               // aliases dead dump region
        pbuf[sl * 32 + oq] = acc;
    }
    __syncthreads();
    if (tid < 32) {
        const float4* pbuf = (const float4*)u;
        float4 r = pbuf[tid];
        #pragma unroll
        for (int s = 1; s < NSL; ++s) {
            const float4 p = pbuf[s * 32 + tid];
            r.x += p.x; r.y += p.y; r.z += p.z; r.w += p.w;
        }
        const float4 bv = ((const float4*)bias)[tid];
        r.x += bv.x; r.y += bv.y; r.z += bv.z; r.w += bv.w;
        ((float4*)(out + (size_t)b * 128))[tid] = r;
    }
}

extern "C" void kernel_launch(void* const* d_in, const int* in_sizes, int n_in,
                              void* d_out, int out_size, void* d_ws, size_t ws_size,
                              hipStream_t stream) {
    const float* inp  = (const float*)d_in[0];
    const float* Wp   = (const float*)d_in[1];
    const float* bias = (const float*)d_in[2];
    float* outp = (float*)d_out;
    (void)in_sizes; (void)n_in; (void)out_size; (void)d_ws; (void)ws_size;

    hipLaunchKernelGGL(signet_fwd, dim3(256), dim3(704), 0, stream,
                       inp, Wp, bias, outp);
}